// Round 9
// baseline (171.114 us; speedup 1.0000x reference)
//
#include <hip/hip_runtime.h>
#include <stdint.h>

typedef __attribute__((ext_vector_type(4))) float f32x4;
typedef __attribute__((ext_vector_type(8))) short bf16x8;
typedef __attribute__((ext_vector_type(4))) short s16x4;
typedef __attribute__((ext_vector_type(4))) float fp32x4;

#define QSCALE 0.18033688f   // 0.125 * log2(e): scores exit QK^T in log2 domain

__device__ __forceinline__ short f2bf(float f) {
    union { float f; unsigned u; } v; v.f = f;
    unsigned u = v.u;
    unsigned r = u + 0x7fffu + ((u >> 16) & 1u);
    return (short)(r >> 16);
}
// packed bf16 convert (RNE), lo = a, hi = b
__device__ __forceinline__ unsigned cvtpk(float a, float b) {
    unsigned r;
    asm("v_cvt_pk_bf16_f32 %0, %1, %2" : "=v"(r) : "v"(a), "v"(b));
    return r;
}

// async global->LDS, 16B per lane. dest = wave-uniform base + lane*16.
__device__ __forceinline__ void gld_lds16(const void* g, void* l) {
    __builtin_amdgcn_global_load_lds(
        (const __attribute__((address_space(1))) unsigned int*)(uintptr_t)g,
        (__attribute__((address_space(3))) unsigned int*)(uintptr_t)l,
        16, 0, 0);
}

// ---------------- fused prep: all casts + RoPE table in ONE launch --------
__global__ __launch_bounds__(256) void prep_kernel(const float* __restrict__ x,
                                                   const float* __restrict__ wq,
                                                   const float* __restrict__ wo,
                                                   short* __restrict__ xb,
                                                   short* __restrict__ wqb,
                                                   short* __restrict__ wob,
                                                   float* __restrict__ tab) {
    int bid = blockIdx.x, tid = threadIdx.x;
    if (bid < 6144) {
        const float* in; short* out; int base;
        if (bid < 4096)      { in = x;  out = xb;  base = bid; }
        else if (bid < 5632) { in = wq; out = wqb; base = bid - 4096; }
        else                 { in = wo; out = wob; base = bid - 5632; }
        int idx = (base * 256 + tid) * 8;
        fp32x4 a = *(const fp32x4*)&in[idx];
        fp32x4 b = *(const fp32x4*)&in[idx + 4];
        union { unsigned w[4]; bf16x8 v; } u;
        u.w[0] = cvtpk(a[0], a[1]); u.w[1] = cvtpk(a[2], a[3]);
        u.w[2] = cvtpk(b[0], b[1]); u.w[3] = cvtpk(b[2], b[3]);
        *(bf16x8*)&out[idx] = u.v;
    } else {
        int idx = (bid - 6144) * 256 + tid;   // 65536
        int l = idx >> 5, d = idx & 31;
        float inv = expf(-(float)d / 32.f * logf(10000.f));
        float ang = (float)l * inv;
        tab[idx * 2 + 0] = cosf(ang);
        tab[idx * 2 + 1] = sinf(ang);
    }
}

// ---------------- GEMM: C[M,N] = A[M,K]*B[N,K]^T + bias, bf16 in ----------
// BM=256 x BN=128, BK=64, 8 waves (4Mx2N), per-wave 64x64 output.
// 3-slot LDS ring (144 KB), counted vmcnt(6) at window top (never 0 in main
// loop), ONE barrier per K-tile: with the 3-slot ring, staging at window T
// writes slot T+2 == slot T-1, whose readers all passed this window's top
// barrier -> the old mid-phase barriers were redundant lockstep. Window:
// {vmcnt(6); barrier; stage 6 || ds_read 16 frags; setprio(1) 32 MFMA}.
// Compiler fine-schedules lgkmcnt between ds_read and MFMA (m97 behavior).
// MODE 0: fp32 out + bias. MODE 1: fused QKV epilogue (RoPE q/k, +QSCALE on
// q, bf16 qkv; v section written transposed to VT[bh][d][L]).
template<int MODE>
__global__ __launch_bounds__(512, 2)
void gemm_bt(const short* __restrict__ A,
             const short* __restrict__ B,
             const float* __restrict__ bias,
             void* __restrict__ Cout,
             short* __restrict__ VTout,
             const float* __restrict__ tab,
             int M, int N, int K) {
    __shared__ short lds[3 * 24576];   // slot = A[256x64] (32KB) + B[128x64] (16KB)
    const int tid = threadIdx.x;
    const int lane = tid & 63, wave = tid >> 6;
    const int i15 = lane & 15, g = lane >> 4;
    const int wr = wave >> 1, wc = wave & 1;

    // bijective XCD chunk-swizzle (nwg % 8 == 0 for all our grids)
    const int nbx = gridDim.x;
    const int nwg = nbx * gridDim.y;
    int bid = blockIdx.y * nbx + blockIdx.x;
    int sw = (bid & 7) * (nwg >> 3) + (bid >> 3);
    const int m0 = (sw / nbx) * 256;
    const int n0 = (sw % nbx) * 128;

    // per-lane LDS read bases: swizzled col = (ks*4+g) ^ (i15&7); split XOR into
    // low2 (g^xr3) and bit2 (ks^xb2) so each ks gets base + imm-offset reads.
    const int xr3 = i15 & 3, xb2 = (i15 >> 2) & 1;
    const int cLo = g ^ xr3;
    const int aoff0 = (wr * 64 + i15) * 64 + (xb2 * 4 + cLo) * 8;
    const int aoff1 = (wr * 64 + i15) * 64 + ((1 ^ xb2) * 4 + cLo) * 8;
    const int boff0 = (wc * 64 + i15) * 64 + (xb2 * 4 + cLo) * 8;
    const int boff1 = (wc * 64 + i15) * 64 + ((1 ^ xb2) * 4 + cLo) * 8;

    // staging sources: thread covers (srow = tid>>3, s = tid&7); row = r*64+srow
    // so row&7 == srow&7 for every r -> one swizzled col per thread.
    const int srow = tid >> 3;
    const int ss = (tid & 7) ^ (srow & 7);
    const short* a0 = A + (size_t)(m0 + srow) * K + ss * 8;
    const short* a1 = a0 + (size_t)64 * K;
    const short* a2 = a0 + (size_t)128 * K;
    const short* a3 = a0 + (size_t)192 * K;
    const short* b0 = B + (size_t)(n0 + srow) * K + ss * 8;
    const short* b1 = b0 + (size_t)64 * K;

#define ST_A(slot, r, p) do { gld_lds16(p, lds + (slot) * 24576 + ((r) * 512 + wave * 64) * 8); p += 64; } while (0)
#define ST_B(slot, r, p) do { gld_lds16(p, lds + (slot) * 24576 + 16384 + ((r) * 512 + wave * 64) * 8); p += 64; } while (0)

    // prologue: K-tiles 0 and 1 into slots 0,1 (12 loads/thread in flight)
    ST_A(0, 0, a0); ST_A(0, 1, a1); ST_B(0, 0, b0);
    ST_A(0, 2, a2); ST_A(0, 3, a3); ST_B(0, 1, b1);
    ST_A(1, 0, a0); ST_A(1, 1, a1); ST_B(1, 0, b0);
    ST_A(1, 2, a2); ST_A(1, 3, a3); ST_B(1, 1, b1);

    f32x4 acc[4][4] = {};
    const int NT = K >> 6;
    int slc = 0;

    for (int T = 0; T < NT; ++T) {
        int stslot = slc + 2; if (stslot >= 3) stslot -= 3;
        // window top: K-tile T landed (own 6 waited + barrier joins all waves);
        // K-tile T+1's 6 loads stay in flight.
        if (T == NT - 1) asm volatile("s_waitcnt vmcnt(0)" ::: "memory");
        else             asm volatile("s_waitcnt vmcnt(6)" ::: "memory");
        __builtin_amdgcn_s_barrier();
        __builtin_amdgcn_sched_barrier(0);

        // stage K-tile T+2 into the slot everyone just finished reading (T-1)
        if (T + 2 < NT) {
            ST_A(stslot, 0, a0); ST_A(stslot, 1, a1);
            ST_A(stslot, 2, a2); ST_A(stslot, 3, a3);
            ST_B(stslot, 0, b0); ST_B(stslot, 1, b1);
        }

        const short* As_ = lds + slc * 24576;
        const short* Bs_ = As_ + 16384;
        bf16x8 af[4][2], bfr[4][2];
#pragma unroll
        for (int m = 0; m < 4; ++m) {
            af[m][0] = *(const bf16x8*)&As_[aoff0 + m * 1024];
            af[m][1] = *(const bf16x8*)&As_[aoff1 + m * 1024];
        }
#pragma unroll
        for (int n = 0; n < 4; ++n) {
            bfr[n][0] = *(const bf16x8*)&Bs_[boff0 + n * 1024];
            bfr[n][1] = *(const bf16x8*)&Bs_[boff1 + n * 1024];
        }
        __builtin_amdgcn_s_setprio(1);
#pragma unroll
        for (int m = 0; m < 4; ++m)
#pragma unroll
            for (int n = 0; n < 4; ++n)
#pragma unroll
                for (int ks = 0; ks < 2; ++ks)
                    acc[m][n] = __builtin_amdgcn_mfma_f32_16x16x32_bf16(af[m][ks], bfr[n][ks], acc[m][n], 0, 0, 0);
        __builtin_amdgcn_s_setprio(0);

        slc = (slc == 2) ? 0 : slc + 1;
    }
#undef ST_A
#undef ST_B

    // epilogue: C row = m0+wr*64+m*16+g*4+j, col = n0+wc*64+n*16+i15
    if (MODE == 0) {
#pragma unroll
        for (int m = 0; m < 4; ++m)
#pragma unroll
            for (int n = 0; n < 4; ++n) {
                int col = n0 + wc * 64 + n * 16 + i15;
                float bcol = bias[col];
#pragma unroll
                for (int j = 0; j < 4; ++j) {
                    int row = m0 + wr * 64 + m * 16 + g * 4 + j;
                    ((float*)Cout)[(size_t)row * N + col] = acc[m][n][j] + bcol;
                }
            }
    } else {
        const int sec = n0 >> 10;        // 0=q, 1=k, 2=v (128-blocks never straddle)
        if (sec < 2) {
            const float qs = (sec == 0) ? QSCALE : 1.0f;
            short* out = (short*)Cout;
#pragma unroll
            for (int m = 0; m < 4; ++m) {
#pragma unroll
                for (int pp = 0; pp < 2; ++pp) {     // pairs (n=pp, n=pp+2): cols d, d+32
                    int d = pp * 16 + i15;
                    int collo = n0 + wc * 64 + pp * 16 + i15;
                    float blo = bias[collo], bhi = bias[collo + 32];
#pragma unroll
                    for (int j = 0; j < 4; ++j) {
                        int row = m0 + wr * 64 + m * 16 + g * 4 + j;
                        int l = row & 2047;
                        float2 cs = *(const float2*)&tab[(l * 32 + d) * 2];
                        float x1 = acc[m][pp][j] + blo;
                        float x2 = acc[m][pp + 2][j] + bhi;
                        out[(size_t)row * 3072 + collo]      = f2bf((x1 * cs.x - x2 * cs.y) * qs);
                        out[(size_t)row * 3072 + collo + 32] = f2bf((x2 * cs.x + x1 * cs.y) * qs);
                    }
                }
            }
        } else {
            // v section: write V^T directly. VT[(b*16+h)*64 + d][l], 4 l per lane.
#pragma unroll
            for (int m = 0; m < 4; ++m) {
                int rbase = m0 + wr * 64 + m * 16 + g * 4;
                int lbase = rbase & 2047, bidx = rbase >> 11;
#pragma unroll
                for (int n = 0; n < 4; ++n) {
                    int vcol = (n0 - 2048) + wc * 64 + n * 16 + i15;
                    int h = vcol >> 6, d = vcol & 63;
                    float bb = bias[n0 + wc * 64 + n * 16 + i15];
                    union { unsigned w[2]; s16x4 v; } u;
                    u.w[0] = cvtpk(acc[m][n][0] + bb, acc[m][n][1] + bb);
                    u.w[1] = cvtpk(acc[m][n][2] + bb, acc[m][n][3] + bb);
                    *(s16x4*)&VTout[((size_t)(bidx * 16 + h) * 64 + d) * 2048 + lbase] = u.v;
                }
            }
        }
    }
}

// ---------------- flash attention (R5-exact: KVBLK=64, 32 KB, 4 blk/CU) ---
// 8 waves x 16 q-rows = 128 q-rows/block; KV tiles of 64, double-buffered.
// S^T = K*Q^T with K rows staged permuted so QK^T output registers ARE the
// PV A-fragment (P never leaves the lane). No max-subtraction (scores O(4)
// in log2 domain); l via ones-MFMA. ONE gld_lds16 for K + one for V per
// thread per tile. Grid = 1024 blocks, XCD-swizzled for per-head L2 reuse.
__global__ __launch_bounds__(512, 8) void attn_kernel(const short* __restrict__ qkv,
                                                      const short* __restrict__ VT,
                                                      short* __restrict__ O) {
    __shared__ short Ks[2][64 * 64];
    __shared__ short Vs[2][64 * 64];
    int orig = blockIdx.x;
    int xcd = orig & 7, idx = orig >> 3;
    int bh = xcd * 8 + (idx >> 4), qt = idx & 15;
    int b = bh >> 4, h = bh & 15;
    int tid = threadIdx.x, lane = tid & 63, wave = tid >> 6;
    int i15 = lane & 15, g = lane >> 4;
    int q0 = qt * 128;

    size_t qrow = (size_t)(b * 2048 + q0 + wave * 16 + i15);
    bf16x8 qf[2];
    qf[0] = *(const bf16x8*)&qkv[qrow * 3072 + h * 64 + 0  + g * 8];
    qf[1] = *(const bf16x8*)&qkv[qrow * 3072 + h * 64 + 32 + g * 8];

    bf16x8 onesf;
#pragma unroll
    for (int e = 0; e < 8; ++e) onesf[e] = (short)0x3F80;   // bf16 1.0

    const int srow = tid >> 3, ss8 = (tid & 7) ^ (srow & 7);
    const int sprow = (srow & 0x23) | ((srow & 0x10) >> 2) | ((srow & 0x0C) << 1); // pi(row)
    const short* kp = qkv + (size_t)(b * 2048) * 3072 + 1024 + h * 64
                      + (size_t)sprow * 3072 + ss8 * 8;
    const short* vp = VT + (size_t)bh * 64 * 2048 + (size_t)srow * 2048 + ss8 * 8;

    const int xr3 = i15 & 3, xb2 = (i15 >> 2) & 1;
    const int cLo = g ^ xr3;
    const int o0 = i15 * 64 + (xb2 * 4 + cLo) * 8;
    const int o1 = i15 * 64 + ((1 ^ xb2) * 4 + cLo) * 8;

    f32x4 acc_o[4] = {};
    f32x4 acc_l = {0.f, 0.f, 0.f, 0.f};

#define STAGE(bk, bv)                                        \
    do {                                                     \
        gld_lds16(kp, (bk) + wave * 512);                    \
        gld_lds16(vp, (bv) + wave * 512);                    \
        kp += 64 * 3072;                                     \
        vp += 64;                                            \
    } while (0)

    STAGE(Ks[0], Vs[0]);

    for (int t = 0; t < 32; ++t) {
        const int cur = t & 1;
        if (t > 0) {
            __builtin_amdgcn_s_barrier();          // all waves done with buf cur^1
            __builtin_amdgcn_sched_barrier(0);
        }
        if (t + 1 < 32) {
            STAGE(Ks[cur ^ 1], Vs[cur ^ 1]);       // 2 vmem ops into other buffer
            asm volatile("s_waitcnt vmcnt(2)" ::: "memory");  // tile t's loads done
        } else {
            asm volatile("s_waitcnt vmcnt(0)" ::: "memory");
        }
        __builtin_amdgcn_s_barrier();              // every wave's tile-t loads landed
        __builtin_amdgcn_sched_barrier(0);

        const short* ks = Ks[cur];
        const short* vs = Vs[cur];

        // S^T = K . Q^T (permuted rows): sa[jb][r] holds kv = kb*32+g*8+e layout
        f32x4 sa[4] = {};
        __builtin_amdgcn_s_setprio(1);
#pragma unroll
        for (int kb = 0; kb < 2; ++kb) {
            const int ko = kb ? o1 : o0;
#pragma unroll
            for (int jb = 0; jb < 4; ++jb) {
                bf16x8 kf = *(const bf16x8*)&ks[ko + jb * 1024];
                sa[jb] = __builtin_amdgcn_mfma_f32_16x16x32_bf16(kf, qf[kb], sa[jb], 0, 0, 0);
            }
        }
        __builtin_amdgcn_s_setprio(0);

        // p = 2^s directly (no max-subtract) — scores are O(4) in log2 domain
        float p[4][4];
#pragma unroll
        for (int jb = 0; jb < 4; ++jb)
#pragma unroll
            for (int r = 0; r < 4; ++r)
                p[jb][r] = __builtin_amdgcn_exp2f(sa[jb][r]);

        // pack P into PV A-fragments in-register: pf[kb] elem e = p[kb*2+(e>>2)][e&3]
        bf16x8 pf[2];
#pragma unroll
        for (int kb = 0; kb < 2; ++kb) {
            union { unsigned w[4]; bf16x8 v; } u;
            u.w[0] = cvtpk(p[2 * kb][0],     p[2 * kb][1]);
            u.w[1] = cvtpk(p[2 * kb][2],     p[2 * kb][3]);
            u.w[2] = cvtpk(p[2 * kb + 1][0], p[2 * kb + 1][1]);
            u.w[3] = cvtpk(p[2 * kb + 1][2], p[2 * kb + 1][3]);
            pf[kb] = u.v;
        }

        // O += P.V ; l += P.1  (both MFMA; same C-layout, no shuffles)
        __builtin_amdgcn_s_setprio(1);
#pragma unroll
        for (int db = 0; db < 4; ++db) {
#pragma unroll
            for (int kb = 0; kb < 2; ++kb) {
                bf16x8 vf = *(const bf16x8*)&vs[(kb ? o1 : o0) + db * 1024];
                acc_o[db] = __builtin_amdgcn_mfma_f32_16x16x32_bf16(pf[kb], vf, acc_o[db], 0, 0, 0);
            }
        }
        acc_l = __builtin_amdgcn_mfma_f32_16x16x32_bf16(pf[0], onesf, acc_l, 0, 0, 0);
        acc_l = __builtin_amdgcn_mfma_f32_16x16x32_bf16(pf[1], onesf, acc_l, 0, 0, 0);
        __builtin_amdgcn_s_setprio(0);
    }
#undef STAGE

    // normalize + store: O row i' = g*4+r; l for that row is acc_l[r]
    float linv4[4];
#pragma unroll
    for (int r = 0; r < 4; ++r) linv4[r] = 1.f / acc_l[r];
#pragma unroll
    for (int db = 0; db < 4; ++db) {
        int ocol = h * 64 + db * 16 + i15;
#pragma unroll
        for (int r = 0; r < 4; ++r) {
            int orow = b * 2048 + q0 + wave * 16 + g * 4 + r;
            O[(size_t)orow * 1024 + ocol] = f2bf(acc_o[db][r] * linv4[r]);
        }
    }
}

extern "C" void kernel_launch(void* const* d_in, const int* in_sizes, int n_in,
                              void* d_out, int out_size, void* d_ws, size_t ws_size,
                              hipStream_t stream) {
    const float* x     = (const float*)d_in[0];
    const float* w_qkv = (const float*)d_in[1];
    const float* b_qkv = (const float*)d_in[2];
    const float* w_out = (const float*)d_in[3];
    const float* b_out = (const float*)d_in[4];

    char* ws = (char*)d_ws;
    short* qkvb = (short*)(ws);                 // 8192*3072*2  = 50331648 (v sec unused)
    short* xb   = (short*)(ws + 50331648);      // 8192*1024*2  = 16777216 (reused as O)
    short* wqb  = (short*)(ws + 67108864);      // 3072*1024*2  =  6291456
    short* wob  = (short*)(ws + 73400320);      // 1024*1024*2  =  2097152
    short* VT   = (short*)(ws + 75497472);      // 64*64*2048*2 = 16777216
    float* rt   = (float*)(ws + 92274688);      // 2048*32*2*4  =   524288
    short* Ob   = xb;                           // reuse x_bf16 region for attn output

    prep_kernel<<<6400, 256, 0, stream>>>(x, w_qkv, w_out, xb, wqb, wob, rt);

    gemm_bt<1><<<dim3(24, 32), 512, 0, stream>>>(xb, wqb, b_qkv, qkvb, VT, rt, 8192, 3072, 1024);
    attn_kernel<<<1024, 512, 0, stream>>>(qkvb, VT, Ob);
    gemm_bt<0><<<dim3(8, 32), 512, 0, stream>>>(Ob, wob, b_out, d_out, nullptr, nullptr, 8192, 1024, 1024);
}

// Round 10
// 162.393 us; speedup vs baseline: 1.0537x; 1.0537x over previous
//
#include <hip/hip_runtime.h>
#include <stdint.h>

typedef __attribute__((ext_vector_type(4))) float f32x4;
typedef __attribute__((ext_vector_type(8))) short bf16x8;
typedef __attribute__((ext_vector_type(4))) short s16x4;
typedef __attribute__((ext_vector_type(4))) float fp32x4;

#define QSCALE 0.18033688f   // 0.125 * log2(e): scores exit QK^T in log2 domain

__device__ __forceinline__ short f2bf(float f) {
    union { float f; unsigned u; } v; v.f = f;
    unsigned u = v.u;
    unsigned r = u + 0x7fffu + ((u >> 16) & 1u);
    return (short)(r >> 16);
}
// packed bf16 convert (RNE), lo = a, hi = b
__device__ __forceinline__ unsigned cvtpk(float a, float b) {
    unsigned r;
    asm("v_cvt_pk_bf16_f32 %0, %1, %2" : "=v"(r) : "v"(a), "v"(b));
    return r;
}

// async global->LDS, 16B per lane. dest = wave-uniform base + lane*16.
__device__ __forceinline__ void gld_lds16(const void* g, void* l) {
    __builtin_amdgcn_global_load_lds(
        (const __attribute__((address_space(1))) unsigned int*)(uintptr_t)g,
        (__attribute__((address_space(3))) unsigned int*)(uintptr_t)l,
        16, 0, 0);
}

// ---------------- fused prep: all casts + RoPE table in ONE launch --------
__global__ __launch_bounds__(256) void prep_kernel(const float* __restrict__ x,
                                                   const float* __restrict__ wq,
                                                   const float* __restrict__ wo,
                                                   short* __restrict__ xb,
                                                   short* __restrict__ wqb,
                                                   short* __restrict__ wob,
                                                   float* __restrict__ tab) {
    int bid = blockIdx.x, tid = threadIdx.x;
    if (bid < 6144) {
        const float* in; short* out; int base;
        if (bid < 4096)      { in = x;  out = xb;  base = bid; }
        else if (bid < 5632) { in = wq; out = wqb; base = bid - 4096; }
        else                 { in = wo; out = wob; base = bid - 5632; }
        int idx = (base * 256 + tid) * 8;
        fp32x4 a = *(const fp32x4*)&in[idx];
        fp32x4 b = *(const fp32x4*)&in[idx + 4];
        union { unsigned w[4]; bf16x8 v; } u;
        u.w[0] = cvtpk(a[0], a[1]); u.w[1] = cvtpk(a[2], a[3]);
        u.w[2] = cvtpk(b[0], b[1]); u.w[3] = cvtpk(b[2], b[3]);
        *(bf16x8*)&out[idx] = u.v;
    } else {
        int idx = (bid - 6144) * 256 + tid;   // 65536
        int l = idx >> 5, d = idx & 31;
        float inv = expf(-(float)d / 32.f * logf(10000.f));
        float ang = (float)l * inv;
        tab[idx * 2 + 0] = cosf(ang);
        tab[idx * 2 + 1] = sinf(ang);
    }
}

// ---------------- GEMM: C[M,N] = A[M,K]*B[N,K]^T + bias, bf16 in ----------
// BM=BN=128, BK=64, 4 waves (2x2), per-wave 64x64 output, 256 threads.
// 2-slot LDS ring = 64 KB -> 2 blocks/CU co-resident: when one block sits at
// its barrier/vmcnt, the other's waves keep the MFMA pipe fed (m97/m114
// mechanism). Window: {barrier; STAGE(T+1) 8 loads; vmcnt(8) [T landed,
// T+1 in flight]; barrier; ds_read 16 frags + 32 MFMA (setprio)}.
// Grids: QKV 24x64=1536 (3 exact rounds), out-proj 8x64=512 (1 round).
// MODE 0: fp32 out + bias. MODE 1: fused QKV epilogue (RoPE q/k, +QSCALE on
// q, bf16 qkv; v section written transposed to VT[bh][d][L]).
template<int MODE>
__global__ __launch_bounds__(256, 2)
void gemm_bt(const short* __restrict__ A,
             const short* __restrict__ B,
             const float* __restrict__ bias,
             void* __restrict__ Cout,
             short* __restrict__ VTout,
             const float* __restrict__ tab,
             int M, int N, int K) {
    __shared__ short lds[2 * 16384];   // slot = A[128x64] (16 KB) + B[128x64] (16 KB)
    const int tid = threadIdx.x;
    const int lane = tid & 63, wave = tid >> 6;
    const int i15 = lane & 15, g = lane >> 4;
    const int wr = wave >> 1, wc = wave & 1;

    // bijective XCD chunk-swizzle (nwg % 8 == 0 for all our grids)
    const int nbx = gridDim.x;
    const int nwg = nbx * gridDim.y;
    int bid = blockIdx.y * nbx + blockIdx.x;
    int sw = (bid & 7) * (nwg >> 3) + (bid >> 3);
    const int m0 = (sw / nbx) * 128;
    const int n0 = (sw % nbx) * 128;

    // per-lane LDS read bases: swizzled col = (ks*4+g) ^ (i15&7); split XOR into
    // low2 (g^xr3) and bit2 (ks^xb2) so each ks gets base + imm-offset reads.
    const int xr3 = i15 & 3, xb2 = (i15 >> 2) & 1;
    const int cLo = g ^ xr3;
    const int aoff0 = (wr * 64 + i15) * 64 + (xb2 * 4 + cLo) * 8;
    const int aoff1 = (wr * 64 + i15) * 64 + ((1 ^ xb2) * 4 + cLo) * 8;
    const int boff0 = (wc * 64 + i15) * 64 + (xb2 * 4 + cLo) * 8;
    const int boff1 = (wc * 64 + i15) * 64 + ((1 ^ xb2) * 4 + cLo) * 8;

    // staging: thread covers rows r*32 + (tid>>3), col-group tid&7, r in 0..3.
    // (r*32+srow)&7 == srow&7 -> one pre-swizzled col per thread.
    const int srow = tid >> 3;
    const int ss = (tid & 7) ^ (srow & 7);
    const short* a0 = A + (size_t)(m0 + srow) * K + ss * 8;
    const short* a1 = a0 + (size_t)32 * K;
    const short* a2 = a0 + (size_t)64 * K;
    const short* a3 = a0 + (size_t)96 * K;
    const short* b0 = B + (size_t)(n0 + srow) * K + ss * 8;
    const short* b1 = b0 + (size_t)32 * K;
    const short* b2 = b0 + (size_t)64 * K;
    const short* b3 = b0 + (size_t)96 * K;

    // dest: A r-chunk at slot*16384 + r*2048 + wave*512 (+ lane*16B); B at +8192
#define STAGE(slot)                                                       \
    do {                                                                  \
        gld_lds16(a0, lds + (slot) * 16384 + 0 * 2048 + wave * 512);      \
        gld_lds16(a1, lds + (slot) * 16384 + 1 * 2048 + wave * 512);      \
        gld_lds16(a2, lds + (slot) * 16384 + 2 * 2048 + wave * 512);      \
        gld_lds16(a3, lds + (slot) * 16384 + 3 * 2048 + wave * 512);      \
        gld_lds16(b0, lds + (slot) * 16384 + 8192 + 0 * 2048 + wave * 512); \
        gld_lds16(b1, lds + (slot) * 16384 + 8192 + 1 * 2048 + wave * 512); \
        gld_lds16(b2, lds + (slot) * 16384 + 8192 + 2 * 2048 + wave * 512); \
        gld_lds16(b3, lds + (slot) * 16384 + 8192 + 3 * 2048 + wave * 512); \
        a0 += 64; a1 += 64; a2 += 64; a3 += 64;                           \
        b0 += 64; b1 += 64; b2 += 64; b3 += 64;                           \
    } while (0)

    STAGE(0);

    f32x4 acc[4][4] = {};
    const int NT = K >> 6;

    for (int T = 0; T < NT; ++T) {
        const int cur = T & 1;
        if (T > 0) {
            __builtin_amdgcn_s_barrier();          // all waves done reading slot cur
            __builtin_amdgcn_sched_barrier(0);
        }
        if (T + 1 < NT) {
            STAGE(cur ^ 1);                        // 8 loads for tile T+1
            asm volatile("s_waitcnt vmcnt(8)" ::: "memory");  // tile T landed
        } else {
            asm volatile("s_waitcnt vmcnt(0)" ::: "memory");
        }
        __builtin_amdgcn_s_barrier();
        __builtin_amdgcn_sched_barrier(0);

        const short* As_ = lds + cur * 16384;
        const short* Bs_ = As_ + 8192;
        bf16x8 af[4][2], bfr[4][2];
#pragma unroll
        for (int m = 0; m < 4; ++m) {
            af[m][0] = *(const bf16x8*)&As_[aoff0 + m * 1024];
            af[m][1] = *(const bf16x8*)&As_[aoff1 + m * 1024];
        }
#pragma unroll
        for (int n = 0; n < 4; ++n) {
            bfr[n][0] = *(const bf16x8*)&Bs_[boff0 + n * 1024];
            bfr[n][1] = *(const bf16x8*)&Bs_[boff1 + n * 1024];
        }
        __builtin_amdgcn_s_setprio(1);
#pragma unroll
        for (int m = 0; m < 4; ++m)
#pragma unroll
            for (int n = 0; n < 4; ++n)
#pragma unroll
                for (int ks = 0; ks < 2; ++ks)
                    acc[m][n] = __builtin_amdgcn_mfma_f32_16x16x32_bf16(af[m][ks], bfr[n][ks], acc[m][n], 0, 0, 0);
        __builtin_amdgcn_s_setprio(0);
    }
#undef STAGE

    // epilogue: C row = m0+wr*64+m*16+g*4+j, col = n0+wc*64+n*16+i15
    if (MODE == 0) {
#pragma unroll
        for (int m = 0; m < 4; ++m)
#pragma unroll
            for (int n = 0; n < 4; ++n) {
                int col = n0 + wc * 64 + n * 16 + i15;
                float bcol = bias[col];
#pragma unroll
                for (int j = 0; j < 4; ++j) {
                    int row = m0 + wr * 64 + m * 16 + g * 4 + j;
                    ((float*)Cout)[(size_t)row * N + col] = acc[m][n][j] + bcol;
                }
            }
    } else {
        const int sec = n0 >> 10;        // 0=q, 1=k, 2=v (128-blocks never straddle)
        if (sec < 2) {
            const float qs = (sec == 0) ? QSCALE : 1.0f;
            short* out = (short*)Cout;
#pragma unroll
            for (int m = 0; m < 4; ++m) {
#pragma unroll
                for (int pp = 0; pp < 2; ++pp) {     // pairs (n=pp, n=pp+2): cols d, d+32
                    int d = pp * 16 + i15;
                    int collo = n0 + wc * 64 + pp * 16 + i15;
                    float blo = bias[collo], bhi = bias[collo + 32];
#pragma unroll
                    for (int j = 0; j < 4; ++j) {
                        int row = m0 + wr * 64 + m * 16 + g * 4 + j;
                        int l = row & 2047;
                        float2 cs = *(const float2*)&tab[(l * 32 + d) * 2];
                        float x1 = acc[m][pp][j] + blo;
                        float x2 = acc[m][pp + 2][j] + bhi;
                        out[(size_t)row * 3072 + collo]      = f2bf((x1 * cs.x - x2 * cs.y) * qs);
                        out[(size_t)row * 3072 + collo + 32] = f2bf((x2 * cs.x + x1 * cs.y) * qs);
                    }
                }
            }
        } else {
            // v section: write V^T directly. VT[(b*16+h)*64 + d][l], 4 l per lane.
#pragma unroll
            for (int m = 0; m < 4; ++m) {
                int rbase = m0 + wr * 64 + m * 16 + g * 4;
                int lbase = rbase & 2047, bidx = rbase >> 11;
#pragma unroll
                for (int n = 0; n < 4; ++n) {
                    int vcol = (n0 - 2048) + wc * 64 + n * 16 + i15;
                    int h = vcol >> 6, d = vcol & 63;
                    float bb = bias[n0 + wc * 64 + n * 16 + i15];
                    union { unsigned w[2]; s16x4 v; } u;
                    u.w[0] = cvtpk(acc[m][n][0] + bb, acc[m][n][1] + bb);
                    u.w[1] = cvtpk(acc[m][n][2] + bb, acc[m][n][3] + bb);
                    *(s16x4*)&VTout[((size_t)(bidx * 16 + h) * 64 + d) * 2048 + lbase] = u.v;
                }
            }
        }
    }
}

// ---------------- flash attention: 32 q-rows per wave --------------------
// 4 waves x 32 q-rows = 128 q-rows/block, 256 threads; KV tiles of 64,
// double-buffered (32 KB). Each wave reads the K/V fragments ONCE per tile
// and feeds TWO Q-groups (qg=0,1) -> LDS-read traffic and barriers per
// q-row are halved vs 16-q-rows/wave (the LDS pipe was the binding
// resource at R9: 16 waves x 16 reads x 8cyc > MFMA cycles).
// S^T = K*Q^T with permuted K rows (QK^T output registers ARE the PV
// A-fragment); p = exp2(s) direct; l via ones-MFMA. Grid 1024 = 4 blk/CU.
__global__ __launch_bounds__(256, 4) void attn_kernel(const short* __restrict__ qkv,
                                                      const short* __restrict__ VT,
                                                      short* __restrict__ O) {
    __shared__ short Ks[2][64 * 64];
    __shared__ short Vs[2][64 * 64];
    int orig = blockIdx.x;
    int xcd = orig & 7, idx = orig >> 3;        // idx in [0,128)
    int bh = xcd * 8 + (idx >> 4), qt = idx & 15;
    int b = bh >> 4, h = bh & 15;
    int tid = threadIdx.x, lane = tid & 63, wave = tid >> 6;
    int i15 = lane & 15, g = lane >> 4;
    int q0 = qt * 128;

    // Q fragments for both q-groups (B-operand: lane col = q-row i15, k = d)
    size_t qbase = (size_t)(b * 2048 + q0 + wave * 32);
    bf16x8 qf[2][2];
#pragma unroll
    for (int qg = 0; qg < 2; ++qg) {
        qf[qg][0] = *(const bf16x8*)&qkv[(qbase + qg * 16 + i15) * 3072 + h * 64 + 0  + g * 8];
        qf[qg][1] = *(const bf16x8*)&qkv[(qbase + qg * 16 + i15) * 3072 + h * 64 + 32 + g * 8];
    }

    bf16x8 onesf;
#pragma unroll
    for (int e = 0; e < 8; ++e) onesf[e] = (short)0x3F80;   // bf16 1.0

    // staging: thread covers rows {srow, srow+32} x col-group (tid&7); K rows
    // pre-permuted by pi, sources pre-swizzled.
    const int srow = tid >> 3;
    const int ss8 = (tid & 7) ^ (srow & 7);
    const int pr0 = (srow & 0x23) | ((srow & 0x10) >> 2) | ((srow & 0x0C) << 1);
    const int sr1 = srow + 32;
    const int pr1 = (sr1 & 0x23) | ((sr1 & 0x10) >> 2) | ((sr1 & 0x0C) << 1);
    const short* kb_ = qkv + (size_t)(b * 2048) * 3072 + 1024 + h * 64 + ss8 * 8;
    const short* kp0 = kb_ + (size_t)pr0 * 3072;
    const short* kp1 = kb_ + (size_t)pr1 * 3072;
    const short* vb_ = VT + (size_t)bh * 64 * 2048 + ss8 * 8;
    const short* vp0 = vb_ + (size_t)srow * 2048;
    const short* vp1 = vb_ + (size_t)sr1 * 2048;

    // per-lane LDS read bases (split-XOR: base + imm offsets)
    const int xr3 = i15 & 3, xb2 = (i15 >> 2) & 1;
    const int cLo = g ^ xr3;
    const int o0 = i15 * 64 + (xb2 * 4 + cLo) * 8;
    const int o1 = i15 * 64 + ((1 ^ xb2) * 4 + cLo) * 8;

    f32x4 acc_o[2][4] = {};
    f32x4 acc_l[2] = {};

#define STAGE(bk, bv)                                        \
    do {                                                     \
        gld_lds16(kp0, (bk) + wave * 512);                   \
        gld_lds16(kp1, (bk) + 2048 + wave * 512);            \
        gld_lds16(vp0, (bv) + wave * 512);                   \
        gld_lds16(vp1, (bv) + 2048 + wave * 512);            \
        kp0 += (size_t)64 * 3072; kp1 += (size_t)64 * 3072;  \
        vp0 += 64; vp1 += 64;                                \
    } while (0)

    STAGE(Ks[0], Vs[0]);

    for (int t = 0; t < 32; ++t) {
        const int cur = t & 1;
        if (t > 0) {
            __builtin_amdgcn_s_barrier();          // all waves done with buf cur^1
            __builtin_amdgcn_sched_barrier(0);
        }
        if (t + 1 < 32) {
            STAGE(Ks[cur ^ 1], Vs[cur ^ 1]);       // 4 vmem ops into other buffer
            asm volatile("s_waitcnt vmcnt(4)" ::: "memory");  // tile t's loads done
        } else {
            asm volatile("s_waitcnt vmcnt(0)" ::: "memory");
        }
        __builtin_amdgcn_s_barrier();              // every wave's tile-t loads landed
        __builtin_amdgcn_sched_barrier(0);

        const short* ks = Ks[cur];
        const short* vs = Vs[cur];

        // S^T = K . Q^T: kf read once, feeds both q-groups
        f32x4 sa[2][4] = {};
        __builtin_amdgcn_s_setprio(1);
#pragma unroll
        for (int kb = 0; kb < 2; ++kb) {
            const int ko = kb ? o1 : o0;
            bf16x8 kf[4];
#pragma unroll
            for (int jb = 0; jb < 4; ++jb) kf[jb] = *(const bf16x8*)&ks[ko + jb * 1024];
#pragma unroll
            for (int qg = 0; qg < 2; ++qg)
#pragma unroll
                for (int jb = 0; jb < 4; ++jb)
                    sa[qg][jb] = __builtin_amdgcn_mfma_f32_16x16x32_bf16(kf[jb], qf[qg][kb], sa[qg][jb], 0, 0, 0);
        }
        __builtin_amdgcn_s_setprio(0);

        // p = 2^s directly (no max-subtract); pack into PV A-fragments
        bf16x8 pf[2][2];
#pragma unroll
        for (int qg = 0; qg < 2; ++qg) {
            float p[4][4];
#pragma unroll
            for (int jb = 0; jb < 4; ++jb)
#pragma unroll
                for (int r = 0; r < 4; ++r)
                    p[jb][r] = __builtin_amdgcn_exp2f(sa[qg][jb][r]);
#pragma unroll
            for (int kb = 0; kb < 2; ++kb) {
                union { unsigned w[4]; bf16x8 v; } u;
                u.w[0] = cvtpk(p[2 * kb][0],     p[2 * kb][1]);
                u.w[1] = cvtpk(p[2 * kb][2],     p[2 * kb][3]);
                u.w[2] = cvtpk(p[2 * kb + 1][0], p[2 * kb + 1][1]);
                u.w[3] = cvtpk(p[2 * kb + 1][2], p[2 * kb + 1][3]);
                pf[qg][kb] = u.v;
            }
        }

        // O += P.V ; l += P.1 — vf read once, feeds both q-groups
        __builtin_amdgcn_s_setprio(1);
#pragma unroll
        for (int db = 0; db < 4; ++db) {
#pragma unroll
            for (int kb = 0; kb < 2; ++kb) {
                bf16x8 vf = *(const bf16x8*)&vs[(kb ? o1 : o0) + db * 1024];
#pragma unroll
                for (int qg = 0; qg < 2; ++qg)
                    acc_o[qg][db] = __builtin_amdgcn_mfma_f32_16x16x32_bf16(pf[qg][kb], vf, acc_o[qg][db], 0, 0, 0);
            }
        }
#pragma unroll
        for (int qg = 0; qg < 2; ++qg) {
            acc_l[qg] = __builtin_amdgcn_mfma_f32_16x16x32_bf16(pf[qg][0], onesf, acc_l[qg], 0, 0, 0);
            acc_l[qg] = __builtin_amdgcn_mfma_f32_16x16x32_bf16(pf[qg][1], onesf, acc_l[qg], 0, 0, 0);
        }
        __builtin_amdgcn_s_setprio(0);
    }
#undef STAGE

    // normalize + store: O row (per qg) = qbase + qg*16 + g*4 + r
#pragma unroll
    for (int qg = 0; qg < 2; ++qg) {
        float linv4[4];
#pragma unroll
        for (int r = 0; r < 4; ++r) linv4[r] = 1.f / acc_l[qg][r];
#pragma unroll
        for (int db = 0; db < 4; ++db) {
            int ocol = h * 64 + db * 16 + i15;
#pragma unroll
            for (int r = 0; r < 4; ++r) {
                size_t orow = qbase + qg * 16 + g * 4 + r;
                O[orow * 1024 + ocol] = f2bf(acc_o[qg][db][r] * linv4[r]);
            }
        }
    }
}

extern "C" void kernel_launch(void* const* d_in, const int* in_sizes, int n_in,
                              void* d_out, int out_size, void* d_ws, size_t ws_size,
                              hipStream_t stream) {
    const float* x     = (const float*)d_in[0];
    const float* w_qkv = (const float*)d_in[1];
    const float* b_qkv = (const float*)d_in[2];
    const float* w_out = (const float*)d_in[3];
    const float* b_out = (const float*)d_in[4];

    char* ws = (char*)d_ws;
    short* qkvb = (short*)(ws);                 // 8192*3072*2  = 50331648 (v sec unused)
    short* xb   = (short*)(ws + 50331648);      // 8192*1024*2  = 16777216 (reused as O)
    short* wqb  = (short*)(ws + 67108864);      // 3072*1024*2  =  6291456
    short* wob  = (short*)(ws + 73400320);      // 1024*1024*2  =  2097152
    short* VT   = (short*)(ws + 75497472);      // 64*64*2048*2 = 16777216
    float* rt   = (float*)(ws + 92274688);      // 2048*32*2*4  =   524288
    short* Ob   = xb;                           // reuse x_bf16 region for attn output

    prep_kernel<<<6400, 256, 0, stream>>>(x, w_qkv, w_out, xb, wqb, wob, rt);

    gemm_bt<1><<<dim3(24, 64), 256, 0, stream>>>(xb, wqb, b_qkv, qkvb, VT, rt, 8192, 3072, 1024);
    attn_kernel<<<1024, 256, 0, stream>>>(qkvb, VT, Ob);
    gemm_bt<0><<<dim3(8, 64), 256, 0, stream>>>(Ob, wob, b_out, d_out, nullptr, nullptr, 8192, 1024, 1024);
}